// Round 7
// baseline (1181.416 us; speedup 1.0000x reference)
//
#include <hip/hip_runtime.h>
#include <stdint.h>
#include <math.h>

typedef unsigned long long u64;
typedef unsigned int u32;
typedef _Float16 half8 __attribute__((ext_vector_type(8)));
typedef float f32x4 __attribute__((ext_vector_type(4)));

#define CC   512
#define HH   50
#define WW2  76
#define PP   3800      // HH*WW2
#define NB   8
#define NA   34200     // PP*9
#define PRE  6000
#define POST 300
#define MWORDS 96      // u64 words per mask row (94 used, padded)
#define NPAD 8192      // bitonic sort size

// ---------------- workspace layout (bytes) ----------------
// wh2   @ 0            65,536      (64 x 512 f16)  [head weights hi]
// wl2   @ 65,536       65,536
// whF   @ 131,072      4,718,592   (frag-major conv weights hi: [g][kk][lane][8])
// wlF   @ 4,849,664    4,718,592
// xh    @ 9,568,256    15,564,800  (4 img * 3800 * 512 f16, per-batch)
// xl    @ 25,133,056   15,564,800
// --- after conv, xh/xl dead; overlay: ---
// O     @ 9,568,256    7,782,400
// boxes @ 17,350,656   4,377,600
// scores@ 21,728,256   1,094,400
// sb    @ 22,822,656     192,000
// bbs   @ 23,014,656     768,000
// areas @ 23,782,656     192,000
// fh    @ 40,697,856   31,129,600
// fl    @ 71,827,456   31,129,600
// --- after k_hgemm, fh/fl dead; overlay: ---
// mask  @ 40,697,856   36,864,000
// peak ~103 MB (<= 115.7 MB proven safe)

__device__ __forceinline__ u32 skey(float f) {
    u32 u = __float_as_uint(f);
    return (u & 0x80000000u) ? ~u : (u | 0x80000000u);
}

__device__ __forceinline__ float4 anchor_at(int p, int a) {
    const float rv[3] = {0.5f, 1.0f, 2.0f};
    const float sv[3] = {8.0f, 16.0f, 32.0f};
    int ri = a / 3, si = a % 3;
    float s16 = 16.0f * sv[si];
    float hh = s16 * sqrtf(rv[ri]);
    float ww = s16 * sqrtf(1.0f / rv[ri]);
    float bx1 = 8.0f - 0.5f * ww, by1 = 8.0f - 0.5f * hh;
    float bx2 = 8.0f + 0.5f * ww, by2 = 8.0f + 0.5f * hh;
    float sx = (float)((p % WW2) * 16);
    float sy = (float)((p / WW2) * 16);
    return make_float4(sx + bx1, sy + by1, sx + bx2, sy + by2);
}

// LDS slot swizzle for A staging: octet j of row m
__device__ __forceinline__ int lds_slot(int m, int j) {
    return (((m >> 4) * 64) + ((m & 15) ^ ((4 * (j & 1)) | (8 * (j >> 1)))) + (j << 4)) << 3;
}

// ---------------- kernel: split x into f16 hi/lo, transposed [p][c] --------------
// grid (119, 16, 4), block (32,8)
__global__ void k_split_x(const float* __restrict__ x, _Float16* __restrict__ xh,
                          _Float16* __restrict__ xl) {
    __shared__ float S[32][33];
    int zim = blockIdx.z;
    int p0 = blockIdx.x * 32, c0 = blockIdx.y * 32;
    int tx = threadIdx.x, ty0 = threadIdx.y;
    const float* xi = x + (size_t)zim * CC * PP;
#pragma unroll
    for (int yy = 0; yy < 32; yy += 8) {
        int cty = c0 + ty0 + yy, ptx = p0 + tx;
        S[ty0 + yy][tx] = (ptx < PP) ? xi[(size_t)cty * PP + ptx] : 0.f;
    }
    __syncthreads();
#pragma unroll
    for (int yy = 0; yy < 32; yy += 8) {
        int p = p0 + ty0 + yy;
        if (p < PP) {
            float v = S[tx][ty0 + yy];
            _Float16 h = (_Float16)v;
            float r = v - (float)h;
            size_t o = (size_t)(zim * PP + p) * 512 + c0 + tx;
            xh[o] = h;
            xl[o] = (_Float16)(r * 2048.0f);
        }
    }
}

// ---------------- kernel: split conv1 weights -> MFMA frag-major hi/lo -----------
// dest[((g*144 + kk)*64 + lane)*8 + j]; g=co>>4, kk=(ci>>5)*9+idx,
// lane=((ci>>3)&3)*16 + (co&15), j=ci&7.  grid 512 (one co per block), block 256.
__global__ void k_split_w(const float* __restrict__ w, _Float16* __restrict__ wh,
                          _Float16* __restrict__ wl) {
    __shared__ float S[4608];
    int co = blockIdx.x;
    for (int t = threadIdx.x; t < 4608; t += 256) S[t] = w[(size_t)co * 4608 + t];
    __syncthreads();
    int g = co >> 4, nlo = co & 15;
    for (int e = threadIdx.x; e < 4608; e += 256) {
        int ci = e >> 3 ? 0 : 0;  // placeholder (removed below)
        (void)ci;
        int cc = e / 9, idx = e - cc * 9;          // e enumerates (ci, idx)
        float v = S[cc * 9 + idx];
        _Float16 h = (_Float16)v;
        float r = v - (float)h;
        int kk = (cc >> 5) * 9 + idx;
        int lane = ((cc >> 3) & 3) * 16 + nlo;
        int j = cc & 7;
        size_t d = (((size_t)g * 144 + kk) * 64 + lane) * 8 + j;
        wh[d] = h;
        wl[d] = (_Float16)(r * 2048.0f);
    }
}

// ---------------- kernel: split head weights into [64][512] f16 hi/lo -----------
__global__ void k_split_w2(const float* __restrict__ lw, const float* __restrict__ sw,
                           _Float16* __restrict__ wh2, _Float16* __restrict__ wl2) {
    int row = blockIdx.x, k = threadIdx.x;
    float v = (row < 36) ? lw[row * 512 + k] : (row < 54 ? sw[(row - 36) * 512 + k] : 0.f);
    _Float16 h = (_Float16)v;
    float r = v - (float)h;
    wh2[row * 512 + k] = h;
    wl2[row * 512 + k] = (_Float16)(r * 2048.0f);
}

// ---------------- kernel: 3x3 conv via split-f16 MFMA implicit GEMM --------------
// 1-D grid 480 (XCD-pinned), block 256 (4 waves, 2x2), BM=BN=128, BK=32.
// A staged in LDS (double-buffered, one barrier/chunk); B direct from global
// in frag-major order (1 KB contiguous per wave-frag, L2-resident per XCD).
__global__ __launch_bounds__(256, 2) void k_conv(
    const _Float16* __restrict__ xh, const _Float16* __restrict__ xl,
    const _Float16* __restrict__ whF, const _Float16* __restrict__ wlF,
    const float* __restrict__ bias, _Float16* __restrict__ fh,
    _Float16* __restrict__ fl, int imgbase)
{
    __shared__ _Float16 lds[2 * 8192];
    const int tid = threadIdx.x;
    const int L = blockIdx.x;
    const int X = L & 7, q = L >> 3;          // q in 0..59
    const int nt = X & 3;
    const int zim = (X >> 2) * 2 + (q >= 30 ? 1 : 0);
    const int mt = q - (q >= 30 ? 30 : 0);
    const int m0 = mt * 128, n0 = nt * 128;
    const _Float16* xhi = xh + (size_t)zim * CC * PP;
    const _Float16* xlo = xl + (size_t)zim * CC * PP;

    const int mA0 = tid >> 2, jA0 = tid & 3;
    const int mA1 = 64 + (tid >> 2);

    f32x4 acc[4][4], acc2[4][4];
#pragma unroll
    for (int i = 0; i < 4; ++i)
#pragma unroll
        for (int j = 0; j < 4; ++j) {
            acc[i][j] = f32x4{0.f, 0.f, 0.f, 0.f};
            acc2[i][j] = f32x4{0.f, 0.f, 0.f, 0.f};
        }

    uint4 pa0h, pa0l, pa1h, pa1l;

    auto ld_a = [&](int m, int idx, int c0, uint4& vh, uint4& vl) {
        int dy = idx / 3 - 1, dx = idx % 3 - 1;
        int p = m0 + m;
        int px = p % 76, py = p / 76;
        bool av = (p < PP) && ((unsigned)(py + dy) < 50u) && ((unsigned)(px + dx) < 76u);
        if (av) {
            size_t off = (size_t)(p + dy * 76 + dx) * 512 + c0 + jA0 * 8;
            vh = *(const uint4*)(xhi + off);
            vl = *(const uint4*)(xlo + off);
        } else {
            vh = make_uint4(0, 0, 0, 0);
            vl = make_uint4(0, 0, 0, 0);
        }
    };
    auto stage_load = [&](int kk) {
        int c9 = kk / 9;                   // c-chunk outer, idx inner
        int idx = kk - c9 * 9;
        int c0 = c9 << 5;
        ld_a(mA0, idx, c0, pa0h, pa0l);
        ld_a(mA1, idx, c0, pa1h, pa1l);
    };
    const int sl0 = lds_slot(mA0, jA0);
    const int sl1 = lds_slot(mA1, jA0);
    auto stage_write = [&](int buf) {
        _Float16* Lp = lds + buf * 8192;
        *(uint4*)(Lp + sl0)        = pa0h;
        *(uint4*)(Lp + 4096 + sl0) = pa0l;
        *(uint4*)(Lp + sl1)        = pa1h;
        *(uint4*)(Lp + 4096 + sl1) = pa1l;
    };

    const int lane = tid & 63, wave = tid >> 6;
    const int wm = wave & 1, wn = wave >> 1;
    const int jr = lane >> 4;
    const int rd_off = (((lane & 15) ^ ((4 * (jr & 1)) | (8 * (jr >> 1)))) + (jr << 4)) << 3;
    const int g0 = nt * 8 + wn * 4;                 // base B frag index
    const size_t lane8 = (size_t)lane * 8;

    auto compute = [&](int buf, int kk) {
        // B frags direct from global (frag-major, 1KB contiguous per wave-frag)
        half8 bh[4], bl[4];
#pragma unroll
        for (int ni = 0; ni < 4; ++ni) {
            size_t off = (((size_t)(g0 + ni) * 144 + kk) * 64) * 8 + lane8;
            bh[ni] = *(const half8*)(whF + off);
            bl[ni] = *(const half8*)(wlF + off);
        }
        const _Float16* Lp = lds + buf * 8192;
        half8 ah[4], al[4];
#pragma unroll
        for (int mi = 0; mi < 4; ++mi) {
            int slot = (((wm * 4 + mi) * 64) << 3) + rd_off;
            ah[mi] = *(const half8*)(Lp + slot);
            al[mi] = *(const half8*)(Lp + 4096 + slot);
        }
#pragma unroll
        for (int ni = 0; ni < 4; ++ni) {
#pragma unroll
            for (int mi = 0; mi < 4; ++mi) {
                acc[mi][ni]  = __builtin_amdgcn_mfma_f32_16x16x32_f16(ah[mi], bh[ni], acc[mi][ni], 0, 0, 0);
                acc2[mi][ni] = __builtin_amdgcn_mfma_f32_16x16x32_f16(ah[mi], bl[ni], acc2[mi][ni], 0, 0, 0);
                acc2[mi][ni] = __builtin_amdgcn_mfma_f32_16x16x32_f16(al[mi], bh[ni], acc2[mi][ni], 0, 0, 0);
            }
        }
    };

    stage_load(0);
    stage_write(0);
    __syncthreads();
    for (int kk = 0; kk < 144; ++kk) {
        int buf = kk & 1;
        if (kk + 1 < 144) stage_load(kk + 1);
        compute(buf, kk);
        if (kk + 1 < 144) stage_write(1 - buf);
        __syncthreads();
    }

    const int qq = lane >> 4, cl = lane & 15;
    const size_t rowbase = (size_t)(imgbase + zim) * PP;
#pragma unroll
    for (int ni = 0; ni < 4; ++ni) {
        int n = n0 + (wn * 4 + ni) * 16 + cl;
        float bs = bias[n];
#pragma unroll
        for (int mi = 0; mi < 4; ++mi) {
            int mb = m0 + (wm * 4 + mi) * 16 + qq * 4;
            if (mb < PP) {
#pragma unroll
                for (int r = 0; r < 4; ++r) {
                    float v = fmaxf(acc[mi][ni][r] + acc2[mi][ni][r] * (1.f / 2048.f) + bs, 0.f);
                    _Float16 h = (_Float16)v;
                    float rr = v - (float)h;
                    size_t o = (rowbase + mb + r) * 512 + n;
                    fh[o] = h;
                    fl[o] = (_Float16)(rr * 2048.0f);
                }
            }
        }
    }
}

// ---------------- kernel: head GEMM via split-f16 MFMA ---------------------------
__global__ __launch_bounds__(256) void k_hgemm(
    const _Float16* __restrict__ fh, const _Float16* __restrict__ fl,
    const _Float16* __restrict__ wh2, const _Float16* __restrict__ wl2,
    const float* __restrict__ lb, const float* __restrict__ sbias,
    float* __restrict__ O)
{
    const int img = blockIdx.y;
    const int p0 = blockIdx.x * 64;
    const int wave = threadIdx.x >> 6, lane = threadIdx.x & 63;
    const int q8 = (lane >> 4) * 8;
    int arow = img * PP + p0 + wave * 16 + (lane & 15);
    if (arow >= NB * PP) arow = NB * PP - 1;
    const _Float16* fhp = fh + (size_t)arow * 512 + q8;
    const _Float16* flp = fl + (size_t)arow * 512 + q8;
    const _Float16* bhp = wh2 + (size_t)(lane & 15) * 512 + q8;
    const _Float16* blp = wl2 + (size_t)(lane & 15) * 512 + q8;

    f32x4 acc[4], acc2[4];
#pragma unroll
    for (int j = 0; j < 4; ++j) {
        acc[j] = f32x4{0.f, 0.f, 0.f, 0.f};
        acc2[j] = f32x4{0.f, 0.f, 0.f, 0.f};
    }

#pragma unroll 4
    for (int k0 = 0; k0 < 512; k0 += 32) {
        half8 ah = *(const half8*)(fhp + k0);
        half8 al = *(const half8*)(flp + k0);
#pragma unroll
        for (int nf = 0; nf < 4; ++nf) {
            half8 bh = *(const half8*)(bhp + (size_t)nf * 16 * 512 + k0);
            half8 bl = *(const half8*)(blp + (size_t)nf * 16 * 512 + k0);
            acc[nf]  = __builtin_amdgcn_mfma_f32_16x16x32_f16(ah, bh, acc[nf], 0, 0, 0);
            acc2[nf] = __builtin_amdgcn_mfma_f32_16x16x32_f16(ah, bl, acc2[nf], 0, 0, 0);
            acc2[nf] = __builtin_amdgcn_mfma_f32_16x16x32_f16(al, bh, acc2[nf], 0, 0, 0);
        }
    }

    const int q = lane >> 4, cl = lane & 15;
#pragma unroll
    for (int nf = 0; nf < 4; ++nf) {
        int n = nf * 16 + cl;
        float bs = (n < 36) ? lb[n] : (n < 54 ? sbias[n - 36] : 0.f);
#pragma unroll
        for (int r = 0; r < 4; ++r) {
            int m = p0 + wave * 16 + q * 4 + r;
            if (m < PP)
                O[((size_t)img * PP + m) * 64 + n] =
                    acc[nf][r] + acc2[nf][r] * (1.f / 2048.f) + bs;
        }
    }
}

// ---------------- kernel: decode heads -> outputs + boxes/scores + anchors -------
__global__ __launch_bounds__(256) void k_post(
    const float* __restrict__ O,
    const int* __restrict__ imh_p, const int* __restrict__ imw_p,
    float* __restrict__ out0, float* __restrict__ out1,
    float* __restrict__ boxes, float* __restrict__ scores,
    float* __restrict__ out3)
{
    int t = blockIdx.x * 256 + threadIdx.x;
    if (t >= NB * NA) return;
    int img = t / NA, r = t % NA;
    int p = r / 9, a = r % 9;
    const float* Op = O + ((size_t)img * PP + p) * 64;
    float4 loc = *(const float4*)(Op + a * 4);
    float2 sc = *(const float2*)(Op + 36 + a * 2);
    size_t ai = (size_t)img * NA + r;
    *(float4*)&out0[ai * 4] = loc;
    *(float2*)&out1[ai * 2] = sc;
    float mx = fmaxf(sc.x, sc.y);
    float e0 = expf(sc.x - mx), e1 = expf(sc.y - mx);
    float fg = e1 / (e0 + e1);
    float fimh = (float)(*imh_p), fimw = (float)(*imw_p);
    float4 an = anchor_at(p, a);
    if (img == 0) ((float4*)out3)[r] = an;
    float aw = an.z - an.x, ah = an.w - an.y;
    float ax = an.x + 0.5f * aw, ay = an.y + 0.5f * ah;
    float cx = loc.x * aw + ax;
    float cy = loc.y * ah + ay;
    float wb = expf(loc.z) * aw, hb = expf(loc.w) * ah;
    float x1 = cx - 0.5f * wb, y1 = cy - 0.5f * hb;
    float x2 = cx + 0.5f * wb, y2 = cy + 0.5f * hb;
    x1 = fminf(fmaxf(x1, 0.f), fimw);
    x2 = fminf(fmaxf(x2, 0.f), fimw);
    y1 = fminf(fmaxf(y1, 0.f), fimh);
    y2 = fminf(fmaxf(y2, 0.f), fimh);
    bool valid = ((x2 - x1) >= 16.0f) && ((y2 - y1) >= 16.0f);
    ((float4*)boxes)[ai] = make_float4(x1, y1, x2, y2);
    scores[ai] = valid ? fg : -INFINITY;
}

// ---------------- kernel: per-image top-6000 select + stable sort (LDS) ----------
__global__ __launch_bounds__(1024) void k_select(
    const float* __restrict__ scores, const float4* __restrict__ boxes,
    float* __restrict__ sb, float4* __restrict__ bbs, float* __restrict__ areas)
{
    extern __shared__ u64 dyn[];
    u64* arr = dyn;
    u32* hist = (u32*)(dyn + NPAD);
    __shared__ u32 s_pref, s_rem, s_cnt;
    int img = blockIdx.x;
    int tid = threadIdx.x;
    const float* sc = scores + (size_t)img * NA;
    if (tid == 0) { s_pref = 0; s_rem = PRE; }
    u32 pmask = 0;
    for (int sh = 24; sh >= 0; sh -= 8) {
        for (int i = tid; i < 256; i += 1024) hist[i] = 0;
        __syncthreads();
        u32 pref = s_pref;
        for (int e = tid; e < NA; e += 1024) {
            u32 k = skey(sc[e]);
            if ((k & pmask) == pref) atomicAdd(&hist[(k >> sh) & 255], 1);
        }
        __syncthreads();
        if (tid == 0) {
            u32 c = 0; u32 rem = s_rem; u32 pv = s_pref;
            for (int d = 255; d >= 0; --d) {
                u32 h = hist[d];
                if (c + h >= rem) { s_pref = pv | ((u32)d << sh); s_rem = rem - c; break; }
                c += h;
            }
        }
        __syncthreads();
        pmask |= (0xFFu << sh);
    }
    u32 T = s_pref;
    if (tid == 0) s_cnt = 0;
    __syncthreads();
    for (int e = tid; e < NA; e += 1024) {
        u32 k = skey(sc[e]);
        if (k >= T) {
            u32 pos = atomicAdd(&s_cnt, 1);
            if (pos < NPAD) arr[pos] = ((u64)k << 32) | (u64)(~(u32)e);
        }
    }
    __syncthreads();
    u32 n = s_cnt; if (n > NPAD) n = NPAD;
    for (u32 t2 = n + tid; t2 < NPAD; t2 += 1024) arr[t2] = 0;
    for (u32 size = 2; size <= NPAD; size <<= 1) {
        for (u32 stride = size >> 1; stride > 0; stride >>= 1) {
            __syncthreads();
            for (u32 t2 = tid; t2 < NPAD / 2; t2 += 1024) {
                u32 i = 2 * t2 - (t2 & (stride - 1));
                u32 j = i + stride;
                u64 a = arr[i], b = arr[j];
                bool desc = ((i & size) == 0);
                if (desc ? (a < b) : (a > b)) { arr[i] = b; arr[j] = a; }
            }
        }
    }
    __syncthreads();
    for (int t2 = tid; t2 < PRE; t2 += 1024) {
        u64 v = arr[t2];
        u32 e = ~(u32)v;
        float s = sc[e];
        float4 bx = boxes[(size_t)img * NA + e];
        sb[img * PRE + t2] = s;
        bbs[img * PRE + t2] = bx;
        areas[img * PRE + t2] = (bx.z - bx.x) * (bx.w - bx.y);
    }
}

// ---------------- kernel: IoU suppression bitmask (upper-triangular tiles) -------
__global__ __launch_bounds__(256) void k_mask(
    const float4* __restrict__ bbs, const float* __restrict__ areas,
    u64* __restrict__ mask)
{
    int img = blockIdx.z, iT = blockIdx.x, jT = blockIdx.y;
    if (jT * 256 + 255 <= iT * 64) return;
    int tid = threadIdx.x;
    __shared__ float4 jb[256];
    __shared__ float ja[256];
    int jj = jT * 256 + tid;
    jb[tid] = (jj < PRE) ? bbs[(size_t)img * PRE + jj] : make_float4(0, 0, 0, 0);
    ja[tid] = (jj < PRE) ? areas[img * PRE + jj] : 0.f;
    __syncthreads();
    int i = iT * 64 + (tid & 63);
    int jw = jT * 4 + (tid >> 6);
    if (i >= PRE) return;
    float4 bi = bbs[(size_t)img * PRE + i];
    float ai = areas[img * PRE + i];
    int j0 = (tid >> 6) * 64;
    u64 m = 0;
#pragma unroll 4
    for (int b = 0; b < 64; ++b) {
        int j = jw * 64 + b;
        if (j >= PRE) break;
        if (j > i) {
            float4 bj = jb[j0 + b];
            float xx1 = fmaxf(bi.x, bj.x), yy1 = fmaxf(bi.y, bj.y);
            float xx2 = fminf(bi.z, bj.z), yy2 = fminf(bi.w, bj.w);
            float iw = fmaxf(xx2 - xx1, 0.f), ih2 = fmaxf(yy2 - yy1, 0.f);
            float inter = iw * ih2;
            float iou = inter / (ai + ja[j0 + b] - inter + 1e-9f);
            if (iou > 0.7f) m |= (1ull << b);
        }
    }
    mask[((size_t)img * PRE + i) * MWORDS + jw] = m;
}

// ---------------- kernel: chunked NMS scan — 64 boxes per serial step ------------
__global__ __launch_bounds__(128) void k_scan(
    const float* __restrict__ sb, const float4* __restrict__ bbs,
    const u64* __restrict__ mask, float* __restrict__ out2)
{
    const int img = blockIdx.x;
    const int tid = threadIdx.x;
    const int lane = tid & 63, wv = tid >> 6;
    __shared__ u64 keep[96];
    __shared__ u64 s_keptw;
    __shared__ int list[POST];
    __shared__ int s_n;

    for (int j0 = 0; j0 < PRE; j0 += 128) {
        int j = j0 + tid;
        bool alive = (j < PRE) && isfinite(sb[(size_t)img * PRE + j]);
        u64 bal = __ballot(alive);
        if (lane == 0) keep[(j0 >> 6) + wv] = bal;
    }
    if (tid == 0) { s_n = 0; keep[94] = 0; keep[95] = 0; }
    __syncthreads();

    const u64* mimg = mask + (size_t)img * PRE * MWORDS;
    for (int w = 0; w < 94; ++w) {
        if (s_n >= POST) break;
        if (wv == 0) {
            u64 myrow = mimg[(size_t)(w * 64 + lane) * MWORDS + w];
            u64 cur = keep[w];
            u64 keptw = 0;
            while (cur) {
                int b = __builtin_ctzll(cur);
                keptw |= 1ull << b;
                u64 row = __shfl(myrow, b);
                u64 hi = (b >= 63) ? 0ull : (~0ull << (b + 1));
                cur &= ~row & hi;
            }
            if (lane == 0) s_keptw = keptw;
        }
        __syncthreads();
        u64 keptw = s_keptw;
        if (tid == 0) {
            int n = s_n;
            u64 bits = keptw;
            while (bits && n < POST) {
                int b = __builtin_ctzll(bits);
                bits &= bits - 1;
                list[n++] = w * 64 + b;
            }
            s_n = n;
        }
        int v = w + 1 + tid;
        if (v < 94 && keptw) {
            u64 supp = 0;
            u64 bits = keptw;
            while (bits) {
                int b = __builtin_ctzll(bits);
                bits &= bits - 1;
                supp |= mimg[(size_t)(w * 64 + b) * MWORDS + v];
            }
            keep[v] &= ~supp;
        }
        __syncthreads();
    }
    __syncthreads();
    int n = s_n;
    for (int e = tid; e < POST; e += 128) {
        float4 bx = (e < n) ? bbs[(size_t)img * PRE + list[e]] : make_float4(0, 0, 0, 0);
        *(float4*)&out2[((size_t)img * POST + e) * 4] = bx;
    }
}

extern "C" void kernel_launch(void* const* d_in, const int* in_sizes, int n_in,
                              void* d_out, int out_size, void* d_ws, size_t ws_size,
                              hipStream_t stream)
{
    const float* x     = (const float*)d_in[0];
    const float* w1    = (const float*)d_in[1];
    const float* b1    = (const float*)d_in[2];
    const float* sw    = (const float*)d_in[3];
    const float* sbias = (const float*)d_in[4];
    const float* lw    = (const float*)d_in[5];
    const float* lb    = (const float*)d_in[6];
    const int*   imh   = (const int*)d_in[7];
    const int*   imw   = (const int*)d_in[8];
    float* out = (float*)d_out;
    char* ws = (char*)d_ws;

    _Float16* wh2W = (_Float16*)(ws + 0);
    _Float16* wl2W = (_Float16*)(ws + 65536);
    _Float16* whW  = (_Float16*)(ws + 131072);
    _Float16* wlW  = (_Float16*)(ws + 4849664);
    _Float16* xhW  = (_Float16*)(ws + 9568256);
    _Float16* xlW  = (_Float16*)(ws + 25133056);
    float*    OW      = (float*)(ws + 9568256);
    float*    boxesW  = (float*)(ws + 17350656);
    float*    scoresW = (float*)(ws + 21728256);
    float*    sbW     = (float*)(ws + 22822656);
    float*    bbsW    = (float*)(ws + 23014656);
    float*    areasW  = (float*)(ws + 23782656);
    _Float16* fhW  = (_Float16*)(ws + 40697856);
    _Float16* flW  = (_Float16*)(ws + 71827456);
    u64*      maskW   = (u64*)(ws + 40697856);

    float* out0 = out;            // rpn_locs   (8,34200,4)
    float* out1 = out + 1094400;  // rpn_scores (8,34200,2)
    float* out2 = out + 1641600;  // rois       (2400,4)
    float* out3 = out + 1651200;  // anchors    (34200,4)

    hipLaunchKernelGGL(k_split_w, dim3(512), dim3(256), 0, stream, w1, whW, wlW);
    hipLaunchKernelGGL(k_split_w2, dim3(64), dim3(512), 0, stream, lw, sw, wh2W, wl2W);
    for (int b = 0; b < 2; ++b) {
        hipLaunchKernelGGL(k_split_x, dim3(119, 16, 4), dim3(32, 8), 0, stream,
                           x + (size_t)b * 4 * CC * PP, xhW, xlW);
        hipLaunchKernelGGL(k_conv, dim3(480), dim3(256), 0, stream,
                           xhW, xlW, whW, wlW, b1, fhW, flW, b * 4);
    }
    hipLaunchKernelGGL(k_hgemm, dim3(60, NB), dim3(256), 0, stream,
                       fhW, flW, wh2W, wl2W, lb, sbias, OW);
    hipLaunchKernelGGL(k_post, dim3((NB * NA + 255) / 256), dim3(256), 0, stream,
                       OW, imh, imw, out0, out1, boxesW, scoresW, out3);
    hipLaunchKernelGGL(k_select, dim3(NB), dim3(1024), NPAD * 8 + 256 * 4, stream,
                       scoresW, (const float4*)boxesW, sbW, (float4*)bbsW, areasW);
    hipLaunchKernelGGL(k_mask, dim3(94, 24, NB), dim3(256), 0, stream,
                       (const float4*)bbsW, areasW, maskW);
    hipLaunchKernelGGL(k_scan, dim3(NB), dim3(128), 0, stream,
                       sbW, (const float4*)bbsW, maskW, out2);
}

// Round 8
// 1020.976 us; speedup vs baseline: 1.1571x; 1.1571x over previous
//
#include <hip/hip_runtime.h>
#include <stdint.h>
#include <math.h>

typedef unsigned long long u64;
typedef unsigned int u32;
typedef _Float16 half8 __attribute__((ext_vector_type(8)));
typedef float f32x4 __attribute__((ext_vector_type(4)));

#define CC   512
#define HH   50
#define WW2  76
#define PP   3800      // HH*WW2
#define NB   8
#define NA   34200     // PP*9
#define PRE  6000
#define POST 300
#define MWORDS 96      // u64 words per mask row (94 used, padded)
#define NPAD 8192      // bitonic sort size

// ---------------- workspace layout (bytes) ----------------
// wh2   @ 0            65,536      (64 x 512 f16)  [head weights hi]
// wl2   @ 65,536       65,536
// whF   @ 131,072      4,718,592   (frag-major conv weights hi: [g][kk][lane][8])
// wlF   @ 4,849,664    4,718,592
// xh    @ 9,568,256    15,564,800  (4 img * 3800 * 512 f16, per-batch)
// xl    @ 25,133,056   15,564,800
// --- after conv, xh/xl dead; overlay: ---
// O     @ 9,568,256    7,782,400
// boxes @ 17,350,656   4,377,600
// scores@ 21,728,256   1,094,400
// sb    @ 22,822,656     192,000
// bbs   @ 23,014,656     768,000
// areas @ 23,782,656     192,000
// fh    @ 40,697,856   31,129,600
// fl    @ 71,827,456   31,129,600
// --- after k_hgemm, fh/fl dead; overlay: ---
// mask  @ 40,697,856   36,864,000
// peak ~103 MB (<= 115.7 MB proven safe)

__device__ __forceinline__ u32 skey(float f) {
    u32 u = __float_as_uint(f);
    return (u & 0x80000000u) ? ~u : (u | 0x80000000u);
}

__device__ __forceinline__ float4 anchor_at(int p, int a) {
    const float rv[3] = {0.5f, 1.0f, 2.0f};
    const float sv[3] = {8.0f, 16.0f, 32.0f};
    int ri = a / 3, si = a % 3;
    float s16 = 16.0f * sv[si];
    float hh = s16 * sqrtf(rv[ri]);
    float ww = s16 * sqrtf(1.0f / rv[ri]);
    float bx1 = 8.0f - 0.5f * ww, by1 = 8.0f - 0.5f * hh;
    float bx2 = 8.0f + 0.5f * ww, by2 = 8.0f + 0.5f * hh;
    float sx = (float)((p % WW2) * 16);
    float sy = (float)((p / WW2) * 16);
    return make_float4(sx + bx1, sy + by1, sx + bx2, sy + by2);
}

// LDS slot swizzle for A staging: octet j of row m
__device__ __forceinline__ int lds_slot(int m, int j) {
    return (((m >> 4) * 64) + ((m & 15) ^ ((4 * (j & 1)) | (8 * (j >> 1)))) + (j << 4)) << 3;
}

// ---------------- kernel: split x into f16 hi/lo, transposed [p][c] --------------
// grid (119, 16, 4), block (32,8)
__global__ void k_split_x(const float* __restrict__ x, _Float16* __restrict__ xh,
                          _Float16* __restrict__ xl) {
    __shared__ float S[32][33];
    int zim = blockIdx.z;
    int p0 = blockIdx.x * 32, c0 = blockIdx.y * 32;
    int tx = threadIdx.x, ty0 = threadIdx.y;
    const float* xi = x + (size_t)zim * CC * PP;
#pragma unroll
    for (int yy = 0; yy < 32; yy += 8) {
        int cty = c0 + ty0 + yy, ptx = p0 + tx;
        S[ty0 + yy][tx] = (ptx < PP) ? xi[(size_t)cty * PP + ptx] : 0.f;
    }
    __syncthreads();
#pragma unroll
    for (int yy = 0; yy < 32; yy += 8) {
        int p = p0 + ty0 + yy;
        if (p < PP) {
            float v = S[tx][ty0 + yy];
            _Float16 h = (_Float16)v;
            float r = v - (float)h;
            size_t o = (size_t)(zim * PP + p) * 512 + c0 + tx;
            xh[o] = h;
            xl[o] = (_Float16)(r * 2048.0f);
        }
    }
}

// ---------------- kernel: split conv1 weights -> MFMA frag-major hi/lo -----------
// dest[((g*144 + kk)*64 + lane)*8 + j]; g=co>>4, kk=(ci>>5)*9+idx,
// lane=((ci>>3)&3)*16 + (co&15), j=ci&7.  grid 512 (one co per block), block 256.
__global__ void k_split_w(const float* __restrict__ w, _Float16* __restrict__ wh,
                          _Float16* __restrict__ wl) {
    __shared__ float S[4608];
    int co = blockIdx.x;
    for (int t = threadIdx.x; t < 4608; t += 256) S[t] = w[(size_t)co * 4608 + t];
    __syncthreads();
    int g = co >> 4, nlo = co & 15;
    for (int e = threadIdx.x; e < 4608; e += 256) {
        int cc = e / 9, idx = e - cc * 9;          // e enumerates (ci, idx)
        float v = S[cc * 9 + idx];
        _Float16 h = (_Float16)v;
        float r = v - (float)h;
        int kk = (cc >> 5) * 9 + idx;
        int lane = ((cc >> 3) & 3) * 16 + nlo;
        int j = cc & 7;
        size_t d = (((size_t)g * 144 + kk) * 64 + lane) * 8 + j;
        wh[d] = h;
        wl[d] = (_Float16)(r * 2048.0f);
    }
}

// ---------------- kernel: split head weights into [64][512] f16 hi/lo -----------
__global__ void k_split_w2(const float* __restrict__ lw, const float* __restrict__ sw,
                           _Float16* __restrict__ wh2, _Float16* __restrict__ wl2) {
    int row = blockIdx.x, k = threadIdx.x;
    float v = (row < 36) ? lw[row * 512 + k] : (row < 54 ? sw[(row - 36) * 512 + k] : 0.f);
    _Float16 h = (_Float16)v;
    float r = v - (float)h;
    wh2[row * 512 + k] = h;
    wl2[row * 512 + k] = (_Float16)(r * 2048.0f);
}

// ---------------- kernel: 3x3 conv via split-f16 MFMA implicit GEMM --------------
// 1-D grid 480 (XCD-pinned), block 256 (4 waves, 2x2), BM=BN=128, BK=32.
// A staged in LDS (double-buffered); B frag-major from global, software-pipelined
// into a double register set (loads for chunk k+1 issued before compute(k)).
__global__ __launch_bounds__(256, 2) void k_conv(
    const _Float16* __restrict__ xh, const _Float16* __restrict__ xl,
    const _Float16* __restrict__ whF, const _Float16* __restrict__ wlF,
    const float* __restrict__ bias, _Float16* __restrict__ fh,
    _Float16* __restrict__ fl, int imgbase)
{
    __shared__ _Float16 lds[2 * 8192];
    const int tid = threadIdx.x;
    const int L = blockIdx.x;
    const int X = L & 7, q = L >> 3;          // q in 0..59
    const int nt = X & 3;
    const int zim = (X >> 2) * 2 + (q >= 30 ? 1 : 0);
    const int mt = q - (q >= 30 ? 30 : 0);
    const int m0 = mt * 128, n0 = nt * 128;
    const _Float16* xhi = xh + (size_t)zim * CC * PP;
    const _Float16* xlo = xl + (size_t)zim * CC * PP;

    const int mA0 = tid >> 2, jA0 = tid & 3;
    const int mA1 = 64 + (tid >> 2);

    f32x4 acc[4][4], acc2[4][4];
#pragma unroll
    for (int i = 0; i < 4; ++i)
#pragma unroll
        for (int j = 0; j < 4; ++j) {
            acc[i][j] = f32x4{0.f, 0.f, 0.f, 0.f};
            acc2[i][j] = f32x4{0.f, 0.f, 0.f, 0.f};
        }

    uint4 pa0h, pa0l, pa1h, pa1l;

    auto ld_a = [&](int m, int idx, int c0, uint4& vh, uint4& vl) {
        int dy = idx / 3 - 1, dx = idx % 3 - 1;
        int p = m0 + m;
        int px = p % 76, py = p / 76;
        bool av = (p < PP) && ((unsigned)(py + dy) < 50u) && ((unsigned)(px + dx) < 76u);
        if (av) {
            size_t off = (size_t)(p + dy * 76 + dx) * 512 + c0 + jA0 * 8;
            vh = *(const uint4*)(xhi + off);
            vl = *(const uint4*)(xlo + off);
        } else {
            vh = make_uint4(0, 0, 0, 0);
            vl = make_uint4(0, 0, 0, 0);
        }
    };
    auto stage_load = [&](int kk) {
        int c9 = kk / 9;                   // c-chunk outer, idx inner
        int idx = kk - c9 * 9;
        int c0 = c9 << 5;
        ld_a(mA0, idx, c0, pa0h, pa0l);
        ld_a(mA1, idx, c0, pa1h, pa1l);
    };
    const int sl0 = lds_slot(mA0, jA0);
    const int sl1 = lds_slot(mA1, jA0);
    auto stage_write = [&](int buf) {
        _Float16* Lp = lds + buf * 8192;
        *(uint4*)(Lp + sl0)        = pa0h;
        *(uint4*)(Lp + 4096 + sl0) = pa0l;
        *(uint4*)(Lp + sl1)        = pa1h;
        *(uint4*)(Lp + 4096 + sl1) = pa1l;
    };

    const int lane = tid & 63, wave = tid >> 6;
    const int wm = wave & 1, wn = wave >> 1;
    const int jr = lane >> 4;
    const int rd_off = (((lane & 15) ^ ((4 * (jr & 1)) | (8 * (jr >> 1)))) + (jr << 4)) << 3;
    const int g0 = nt * 8 + wn * 4;                 // base B frag index
    const size_t lane8 = (size_t)lane * 8;

    half8 b0h[4], b0l[4], b1h[4], b1l[4];
    auto load_b = [&](int kk, half8* bh_, half8* bl_) {
#pragma unroll
        for (int ni = 0; ni < 4; ++ni) {
            size_t off = (((size_t)(g0 + ni) * 144 + kk) * 64) * 8 + lane8;
            bh_[ni] = *(const half8*)(whF + off);
            bl_[ni] = *(const half8*)(wlF + off);
        }
    };

    auto compute = [&](int buf, const half8* bh, const half8* bl) {
        const _Float16* Lp = lds + buf * 8192;
        half8 ah[4], al[4];
#pragma unroll
        for (int mi = 0; mi < 4; ++mi) {
            int slot = (((wm * 4 + mi) * 64) << 3) + rd_off;
            ah[mi] = *(const half8*)(Lp + slot);
            al[mi] = *(const half8*)(Lp + 4096 + slot);
        }
#pragma unroll
        for (int ni = 0; ni < 4; ++ni) {
#pragma unroll
            for (int mi = 0; mi < 4; ++mi) {
                acc[mi][ni]  = __builtin_amdgcn_mfma_f32_16x16x32_f16(ah[mi], bh[ni], acc[mi][ni], 0, 0, 0);
                acc2[mi][ni] = __builtin_amdgcn_mfma_f32_16x16x32_f16(ah[mi], bl[ni], acc2[mi][ni], 0, 0, 0);
                acc2[mi][ni] = __builtin_amdgcn_mfma_f32_16x16x32_f16(al[mi], bh[ni], acc2[mi][ni], 0, 0, 0);
            }
        }
    };

    stage_load(0);
    stage_write(0);
    load_b(0, b0h, b0l);
    __syncthreads();
    // K loop unrolled by 2: explicit register ping-pong for B (no copies)
    for (int kk = 0; kk < 144; kk += 2) {
        // chunk kk (A buf = 0)
        stage_load(kk + 1);
        load_b(kk + 1, b1h, b1l);
        compute(0, b0h, b0l);
        stage_write(1);
        __syncthreads();
        // chunk kk+1 (A buf = 1)
        if (kk + 2 < 144) {
            stage_load(kk + 2);
            load_b(kk + 2, b0h, b0l);
        }
        compute(1, b1h, b1l);
        if (kk + 2 < 144) stage_write(0);
        __syncthreads();
    }

    const int qq = lane >> 4, cl = lane & 15;
    const size_t rowbase = (size_t)(imgbase + zim) * PP;
#pragma unroll
    for (int ni = 0; ni < 4; ++ni) {
        int n = n0 + (wn * 4 + ni) * 16 + cl;
        float bs = bias[n];
#pragma unroll
        for (int mi = 0; mi < 4; ++mi) {
            int mb = m0 + (wm * 4 + mi) * 16 + qq * 4;
            if (mb < PP) {
#pragma unroll
                for (int r = 0; r < 4; ++r) {
                    float v = fmaxf(acc[mi][ni][r] + acc2[mi][ni][r] * (1.f / 2048.f) + bs, 0.f);
                    _Float16 h = (_Float16)v;
                    float rr = v - (float)h;
                    size_t o = (rowbase + mb + r) * 512 + n;
                    fh[o] = h;
                    fl[o] = (_Float16)(rr * 2048.0f);
                }
            }
        }
    }
}

// ---------------- kernel: head GEMM via split-f16 MFMA ---------------------------
__global__ __launch_bounds__(256) void k_hgemm(
    const _Float16* __restrict__ fh, const _Float16* __restrict__ fl,
    const _Float16* __restrict__ wh2, const _Float16* __restrict__ wl2,
    const float* __restrict__ lb, const float* __restrict__ sbias,
    float* __restrict__ O)
{
    const int img = blockIdx.y;
    const int p0 = blockIdx.x * 64;
    const int wave = threadIdx.x >> 6, lane = threadIdx.x & 63;
    const int q8 = (lane >> 4) * 8;
    int arow = img * PP + p0 + wave * 16 + (lane & 15);
    if (arow >= NB * PP) arow = NB * PP - 1;
    const _Float16* fhp = fh + (size_t)arow * 512 + q8;
    const _Float16* flp = fl + (size_t)arow * 512 + q8;
    const _Float16* bhp = wh2 + (size_t)(lane & 15) * 512 + q8;
    const _Float16* blp = wl2 + (size_t)(lane & 15) * 512 + q8;

    f32x4 acc[4], acc2[4];
#pragma unroll
    for (int j = 0; j < 4; ++j) {
        acc[j] = f32x4{0.f, 0.f, 0.f, 0.f};
        acc2[j] = f32x4{0.f, 0.f, 0.f, 0.f};
    }

#pragma unroll 4
    for (int k0 = 0; k0 < 512; k0 += 32) {
        half8 ah = *(const half8*)(fhp + k0);
        half8 al = *(const half8*)(flp + k0);
#pragma unroll
        for (int nf = 0; nf < 4; ++nf) {
            half8 bh = *(const half8*)(bhp + (size_t)nf * 16 * 512 + k0);
            half8 bl = *(const half8*)(blp + (size_t)nf * 16 * 512 + k0);
            acc[nf]  = __builtin_amdgcn_mfma_f32_16x16x32_f16(ah, bh, acc[nf], 0, 0, 0);
            acc2[nf] = __builtin_amdgcn_mfma_f32_16x16x32_f16(ah, bl, acc2[nf], 0, 0, 0);
            acc2[nf] = __builtin_amdgcn_mfma_f32_16x16x32_f16(al, bh, acc2[nf], 0, 0, 0);
        }
    }

    const int q = lane >> 4, cl = lane & 15;
#pragma unroll
    for (int nf = 0; nf < 4; ++nf) {
        int n = nf * 16 + cl;
        float bs = (n < 36) ? lb[n] : (n < 54 ? sbias[n - 36] : 0.f);
#pragma unroll
        for (int r = 0; r < 4; ++r) {
            int m = p0 + wave * 16 + q * 4 + r;
            if (m < PP)
                O[((size_t)img * PP + m) * 64 + n] =
                    acc[nf][r] + acc2[nf][r] * (1.f / 2048.f) + bs;
        }
    }
}

// ---------------- kernel: decode heads -> outputs + boxes/scores + anchors -------
__global__ __launch_bounds__(256) void k_post(
    const float* __restrict__ O,
    const int* __restrict__ imh_p, const int* __restrict__ imw_p,
    float* __restrict__ out0, float* __restrict__ out1,
    float* __restrict__ boxes, float* __restrict__ scores,
    float* __restrict__ out3)
{
    int t = blockIdx.x * 256 + threadIdx.x;
    if (t >= NB * NA) return;
    int img = t / NA, r = t % NA;
    int p = r / 9, a = r % 9;
    const float* Op = O + ((size_t)img * PP + p) * 64;
    float4 loc = *(const float4*)(Op + a * 4);
    float2 sc = *(const float2*)(Op + 36 + a * 2);
    size_t ai = (size_t)img * NA + r;
    *(float4*)&out0[ai * 4] = loc;
    *(float2*)&out1[ai * 2] = sc;
    float mx = fmaxf(sc.x, sc.y);
    float e0 = expf(sc.x - mx), e1 = expf(sc.y - mx);
    float fg = e1 / (e0 + e1);
    float fimh = (float)(*imh_p), fimw = (float)(*imw_p);
    float4 an = anchor_at(p, a);
    if (img == 0) ((float4*)out3)[r] = an;
    float aw = an.z - an.x, ah = an.w - an.y;
    float ax = an.x + 0.5f * aw, ay = an.y + 0.5f * ah;
    float cx = loc.x * aw + ax;
    float cy = loc.y * ah + ay;
    float wb = expf(loc.z) * aw, hb = expf(loc.w) * ah;
    float x1 = cx - 0.5f * wb, y1 = cy - 0.5f * hb;
    float x2 = cx + 0.5f * wb, y2 = cy + 0.5f * hb;
    x1 = fminf(fmaxf(x1, 0.f), fimw);
    x2 = fminf(fmaxf(x2, 0.f), fimw);
    y1 = fminf(fmaxf(y1, 0.f), fimh);
    y2 = fminf(fmaxf(y2, 0.f), fimh);
    bool valid = ((x2 - x1) >= 16.0f) && ((y2 - y1) >= 16.0f);
    ((float4*)boxes)[ai] = make_float4(x1, y1, x2, y2);
    scores[ai] = valid ? fg : -INFINITY;
}

// ---------------- kernel: per-image top-6000 select + stable sort (LDS) ----------
// float4-vectorized histogram/collect sweeps (NA % 4 == 0).
__global__ __launch_bounds__(1024) void k_select(
    const float* __restrict__ scores, const float4* __restrict__ boxes,
    float* __restrict__ sb, float4* __restrict__ bbs, float* __restrict__ areas)
{
    extern __shared__ u64 dyn[];
    u64* arr = dyn;
    u32* hist = (u32*)(dyn + NPAD);
    __shared__ u32 s_pref, s_rem, s_cnt;
    int img = blockIdx.x;
    int tid = threadIdx.x;
    const float* sc = scores + (size_t)img * NA;
    const float4* sc4 = (const float4*)sc;
    if (tid == 0) { s_pref = 0; s_rem = PRE; }
    u32 pmask = 0;
    for (int sh = 24; sh >= 0; sh -= 8) {
        for (int i = tid; i < 256; i += 1024) hist[i] = 0;
        __syncthreads();
        u32 pref = s_pref;
        for (int e4 = tid; e4 < NA / 4; e4 += 1024) {
            float4 s4 = sc4[e4];
            u32 k0 = skey(s4.x), k1 = skey(s4.y), k2 = skey(s4.z), k3 = skey(s4.w);
            if ((k0 & pmask) == pref) atomicAdd(&hist[(k0 >> sh) & 255], 1);
            if ((k1 & pmask) == pref) atomicAdd(&hist[(k1 >> sh) & 255], 1);
            if ((k2 & pmask) == pref) atomicAdd(&hist[(k2 >> sh) & 255], 1);
            if ((k3 & pmask) == pref) atomicAdd(&hist[(k3 >> sh) & 255], 1);
        }
        __syncthreads();
        if (tid == 0) {
            u32 c = 0; u32 rem = s_rem; u32 pv = s_pref;
            for (int d = 255; d >= 0; --d) {
                u32 h = hist[d];
                if (c + h >= rem) { s_pref = pv | ((u32)d << sh); s_rem = rem - c; break; }
                c += h;
            }
        }
        __syncthreads();
        pmask |= (0xFFu << sh);
    }
    u32 T = s_pref;
    if (tid == 0) s_cnt = 0;
    __syncthreads();
    for (int e4 = tid; e4 < NA / 4; e4 += 1024) {
        float4 s4 = sc4[e4];
        u32 ks[4] = {skey(s4.x), skey(s4.y), skey(s4.z), skey(s4.w)};
#pragma unroll
        for (int v = 0; v < 4; ++v) {
            if (ks[v] >= T) {
                u32 pos = atomicAdd(&s_cnt, 1);
                if (pos < NPAD) arr[pos] = ((u64)ks[v] << 32) | (u64)(~(u32)(e4 * 4 + v));
            }
        }
    }
    __syncthreads();
    u32 n = s_cnt; if (n > NPAD) n = NPAD;
    for (u32 t2 = n + tid; t2 < NPAD; t2 += 1024) arr[t2] = 0;
    for (u32 size = 2; size <= NPAD; size <<= 1) {
        for (u32 stride = size >> 1; stride > 0; stride >>= 1) {
            __syncthreads();
            for (u32 t2 = tid; t2 < NPAD / 2; t2 += 1024) {
                u32 i = 2 * t2 - (t2 & (stride - 1));
                u32 j = i + stride;
                u64 a = arr[i], b = arr[j];
                bool desc = ((i & size) == 0);
                if (desc ? (a < b) : (a > b)) { arr[i] = b; arr[j] = a; }
            }
        }
    }
    __syncthreads();
    for (int t2 = tid; t2 < PRE; t2 += 1024) {
        u64 v = arr[t2];
        u32 e = ~(u32)v;
        float s = sc[e];
        float4 bx = boxes[(size_t)img * NA + e];
        sb[img * PRE + t2] = s;
        bbs[img * PRE + t2] = bx;
        areas[img * PRE + t2] = (bx.z - bx.x) * (bx.w - bx.y);
    }
}

// ---------------- kernel: IoU suppression bitmask (upper-triangular tiles) -------
__global__ __launch_bounds__(256) void k_mask(
    const float4* __restrict__ bbs, const float* __restrict__ areas,
    u64* __restrict__ mask)
{
    int img = blockIdx.z, iT = blockIdx.x, jT = blockIdx.y;
    if (jT * 256 + 255 <= iT * 64) return;
    int tid = threadIdx.x;
    __shared__ float4 jb[256];
    __shared__ float ja[256];
    int jj = jT * 256 + tid;
    jb[tid] = (jj < PRE) ? bbs[(size_t)img * PRE + jj] : make_float4(0, 0, 0, 0);
    ja[tid] = (jj < PRE) ? areas[img * PRE + jj] : 0.f;
    __syncthreads();
    int i = iT * 64 + (tid & 63);
    int jw = jT * 4 + (tid >> 6);
    if (i >= PRE) return;
    float4 bi = bbs[(size_t)img * PRE + i];
    float ai = areas[img * PRE + i];
    int j0 = (tid >> 6) * 64;
    u64 m = 0;
#pragma unroll 4
    for (int b = 0; b < 64; ++b) {
        int j = jw * 64 + b;
        if (j >= PRE) break;
        if (j > i) {
            float4 bj = jb[j0 + b];
            float xx1 = fmaxf(bi.x, bj.x), yy1 = fmaxf(bi.y, bj.y);
            float xx2 = fminf(bi.z, bj.z), yy2 = fminf(bi.w, bj.w);
            float iw = fmaxf(xx2 - xx1, 0.f), ih2 = fmaxf(yy2 - yy1, 0.f);
            float inter = iw * ih2;
            float iou = inter / (ai + ja[j0 + b] - inter + 1e-9f);
            if (iou > 0.7f) m |= (1ull << b);
        }
    }
    mask[((size_t)img * PRE + i) * MWORDS + jw] = m;
}

// ---------------- kernel: chunked NMS scan — 64 boxes per serial step ------------
__global__ __launch_bounds__(128) void k_scan(
    const float* __restrict__ sb, const float4* __restrict__ bbs,
    const u64* __restrict__ mask, float* __restrict__ out2)
{
    const int img = blockIdx.x;
    const int tid = threadIdx.x;
    const int lane = tid & 63, wv = tid >> 6;
    __shared__ u64 keep[96];
    __shared__ u64 s_keptw;
    __shared__ int list[POST];
    __shared__ int s_n;

    for (int j0 = 0; j0 < PRE; j0 += 128) {
        int j = j0 + tid;
        bool alive = (j < PRE) && isfinite(sb[(size_t)img * PRE + j]);
        u64 bal = __ballot(alive);
        if (lane == 0) keep[(j0 >> 6) + wv] = bal;
    }
    if (tid == 0) { s_n = 0; keep[94] = 0; keep[95] = 0; }
    __syncthreads();

    const u64* mimg = mask + (size_t)img * PRE * MWORDS;
    for (int w = 0; w < 94; ++w) {
        if (s_n >= POST) break;
        if (wv == 0) {
            u64 myrow = mimg[(size_t)(w * 64 + lane) * MWORDS + w];
            u64 cur = keep[w];
            u64 keptw = 0;
            while (cur) {
                int b = __builtin_ctzll(cur);
                keptw |= 1ull << b;
                u64 row = __shfl(myrow, b);
                u64 hi = (b >= 63) ? 0ull : (~0ull << (b + 1));
                cur &= ~row & hi;
            }
            if (lane == 0) s_keptw = keptw;
        }
        __syncthreads();
        u64 keptw = s_keptw;
        if (tid == 0) {
            int n = s_n;
            u64 bits = keptw;
            while (bits && n < POST) {
                int b = __builtin_ctzll(bits);
                bits &= bits - 1;
                list[n++] = w * 64 + b;
            }
            s_n = n;
        }
        int v = w + 1 + tid;
        if (v < 94 && keptw) {
            u64 supp = 0;
            u64 bits = keptw;
            while (bits) {
                int b = __builtin_ctzll(bits);
                bits &= bits - 1;
                supp |= mimg[(size_t)(w * 64 + b) * MWORDS + v];
            }
            keep[v] &= ~supp;
        }
        __syncthreads();
    }
    __syncthreads();
    int n = s_n;
    for (int e = tid; e < POST; e += 128) {
        float4 bx = (e < n) ? bbs[(size_t)img * PRE + list[e]] : make_float4(0, 0, 0, 0);
        *(float4*)&out2[((size_t)img * POST + e) * 4] = bx;
    }
}

extern "C" void kernel_launch(void* const* d_in, const int* in_sizes, int n_in,
                              void* d_out, int out_size, void* d_ws, size_t ws_size,
                              hipStream_t stream)
{
    const float* x     = (const float*)d_in[0];
    const float* w1    = (const float*)d_in[1];
    const float* b1    = (const float*)d_in[2];
    const float* sw    = (const float*)d_in[3];
    const float* sbias = (const float*)d_in[4];
    const float* lw    = (const float*)d_in[5];
    const float* lb    = (const float*)d_in[6];
    const int*   imh   = (const int*)d_in[7];
    const int*   imw   = (const int*)d_in[8];
    float* out = (float*)d_out;
    char* ws = (char*)d_ws;

    _Float16* wh2W = (_Float16*)(ws + 0);
    _Float16* wl2W = (_Float16*)(ws + 65536);
    _Float16* whW  = (_Float16*)(ws + 131072);
    _Float16* wlW  = (_Float16*)(ws + 4849664);
    _Float16* xhW  = (_Float16*)(ws + 9568256);
    _Float16* xlW  = (_Float16*)(ws + 25133056);
    float*    OW      = (float*)(ws + 9568256);
    float*    boxesW  = (float*)(ws + 17350656);
    float*    scoresW = (float*)(ws + 21728256);
    float*    sbW     = (float*)(ws + 22822656);
    float*    bbsW    = (float*)(ws + 23014656);
    float*    areasW  = (float*)(ws + 23782656);
    _Float16* fhW  = (_Float16*)(ws + 40697856);
    _Float16* flW  = (_Float16*)(ws + 71827456);
    u64*      maskW   = (u64*)(ws + 40697856);

    float* out0 = out;            // rpn_locs   (8,34200,4)
    float* out1 = out + 1094400;  // rpn_scores (8,34200,2)
    float* out2 = out + 1641600;  // rois       (2400,4)
    float* out3 = out + 1651200;  // anchors    (34200,4)

    hipLaunchKernelGGL(k_split_w, dim3(512), dim3(256), 0, stream, w1, whW, wlW);
    hipLaunchKernelGGL(k_split_w2, dim3(64), dim3(512), 0, stream, lw, sw, wh2W, wl2W);
    for (int b = 0; b < 2; ++b) {
        hipLaunchKernelGGL(k_split_x, dim3(119, 16, 4), dim3(32, 8), 0, stream,
                           x + (size_t)b * 4 * CC * PP, xhW, xlW);
        hipLaunchKernelGGL(k_conv, dim3(480), dim3(256), 0, stream,
                           xhW, xlW, whW, wlW, b1, fhW, flW, b * 4);
    }
    hipLaunchKernelGGL(k_hgemm, dim3(60, NB), dim3(256), 0, stream,
                       fhW, flW, wh2W, wl2W, lb, sbias, OW);
    hipLaunchKernelGGL(k_post, dim3((NB * NA + 255) / 256), dim3(256), 0, stream,
                       OW, imh, imw, out0, out1, boxesW, scoresW, out3);
    hipLaunchKernelGGL(k_select, dim3(NB), dim3(1024), NPAD * 8 + 256 * 4, stream,
                       scoresW, (const float4*)boxesW, sbW, (float4*)bbsW, areasW);
    hipLaunchKernelGGL(k_mask, dim3(94, 24, NB), dim3(256), 0, stream,
                       (const float4*)bbsW, areasW, maskW);
    hipLaunchKernelGGL(k_scan, dim3(NB), dim3(128), 0, stream,
                       sbW, (const float4*)bbsW, maskW, out2);
}